// Round 10
// baseline (1341.259 us; speedup 1.0000x reference)
//
#include <hip/hip_runtime.h>
#include <math.h>

// SNN: 5 LIF layers, B=2048, dims 100->128->256->512->1024->784, 25 steps.
// Round 17: rounds 15/16 proved the compiler COLLAPSES source-level register
// pipelines: VGPR stayed 136 in both (a real depth-4 needs ~200+: 128 buf +
// 32 acc + 16 mem), MfmaUtil stuck at 8.7%, ~4500 cyc/tile of exposed
// load latency. Plain-C++ loads can be legally sunk to their use point.
// Fix (AITER/HK counted-vmcnt pattern, register form): pin the pipeline
// with inline-asm global_load_dwordx4 (asm volatile order is preserved),
// explicit s_waitcnt vmcnt(3L) per slot (L = loads/tile), and
// sched_barrier(0) after each wait (rule: MFMAs otherwise hoist past an
// asm waitcnt -- they don't touch memory). 4 static buffers, 4L loads in
// flight at steady state; each slot waits only for loads issued ~4 slots
// (~600-800 cyc) earlier. Tail drains 3L->2L->L->0. Epilogue stores add to
// vmcnt -> the slot after an epilogue over-waits once per step (accepted,
// ~15k cyc total). NK=2 (L2, trivial) keeps the plain path.
// Numerics bit-identical (same tile/K order and op chain).

typedef _Float16 f16;
typedef __attribute__((ext_vector_type(8))) short short8;
typedef __attribute__((ext_vector_type(8))) _Float16 half8;
typedef __attribute__((ext_vector_type(4))) _Float16 half4;
typedef __attribute__((ext_vector_type(4))) float f32x4;

#define B_TOTAL 2048
#define LO_SCALE 2.44140625e-4f  // 2^-12, undoes the lo x2^12 storage scale
#define ACC_SCALE 0.015625f      // 2^-6, undoes the x64 weight pre-scale

// ---------- pinned 16B global load (issue order preserved) -----------------
__device__ __forceinline__ half8 gld16(const f16* p) {
  half8 r;
  asm volatile("global_load_dwordx4 %0, %1, off" : "=v"(r) : "v"(p));
  return r;
}

// ---------- counted vmcnt wait + scheduling fence --------------------------
template <int N>
__device__ __forceinline__ void vmwait() {
  if constexpr (N == 0)  asm volatile("s_waitcnt vmcnt(0)" ::: "memory");
  else if constexpr (N == 4)  asm volatile("s_waitcnt vmcnt(4)" ::: "memory");
  else if constexpr (N == 8)  asm volatile("s_waitcnt vmcnt(8)" ::: "memory");
  else if constexpr (N == 12) asm volatile("s_waitcnt vmcnt(12)" ::: "memory");
  else if constexpr (N == 16) asm volatile("s_waitcnt vmcnt(16)" ::: "memory");
  else if constexpr (N == 24) asm volatile("s_waitcnt vmcnt(24)" ::: "memory");
  else static_assert(N == 0, "unsupported vmcnt literal");
  __builtin_amdgcn_sched_barrier(0);
}

// ---------- fp32 64x64 GEMM + relu (layer-1 current, runs once) ------------
__global__ __launch_bounds__(256) void gemm_relu_f32_kernel(
    const float* __restrict__ h, const float* __restrict__ W,
    const float* __restrict__ bias, float* __restrict__ out, int N, int K) {
  __shared__ float As[16][64];
  __shared__ float Bs[16][64];

  const int t = threadIdx.x;
  const int tx = t & 15;
  const int ty = t >> 4;
  const int m0 = blockIdx.y * 64;
  const int n0 = blockIdx.x * 64;
  const int lr = t >> 2;
  const int lc = (t & 3) * 4;

  float acc[4][4];
#pragma unroll
  for (int i = 0; i < 4; ++i)
#pragma unroll
    for (int j = 0; j < 4; ++j) acc[i][j] = 0.0f;

  const int ktiles = (K + 15) / 16;
  for (int kt = 0; kt < ktiles; ++kt) {
    const int kbase = kt * 16;
    {
      const float* src = h + (size_t)(m0 + lr) * K + kbase + lc;
#pragma unroll
      for (int j = 0; j < 4; ++j) {
        const int kg = kbase + lc + j;
        As[lc + j][lr] = (kg < K) ? src[j] : 0.0f;
      }
    }
    {
      const int nr = n0 + lr;
      const float* src = W + (size_t)nr * K + kbase + lc;
#pragma unroll
      for (int j = 0; j < 4; ++j) {
        const int kg = kbase + lc + j;
        Bs[lc + j][lr] = (nr < N && kg < K) ? src[j] : 0.0f;
      }
    }
    __syncthreads();
#pragma unroll
    for (int k = 0; k < 16; ++k) {
      float a[4], bb[4];
#pragma unroll
      for (int i = 0; i < 4; ++i) a[i] = As[k][ty * 4 + i];
#pragma unroll
      for (int j = 0; j < 4; ++j) bb[j] = Bs[k][tx * 4 + j];
#pragma unroll
      for (int i = 0; i < 4; ++i)
#pragma unroll
        for (int j = 0; j < 4; ++j) acc[i][j] = fmaf(a[i], bb[j], acc[i][j]);
    }
    __syncthreads();
  }

#pragma unroll
  for (int i = 0; i < 4; ++i) {
    const int m = m0 + ty * 4 + i;
#pragma unroll
    for (int j = 0; j < 4; ++j) {
      const int n = n0 + tx * 4 + j;
      if (n < N) {
        float cur = acc[i][j] + bias[n];
        out[(size_t)m * N + n] = cur > 0.0f ? cur : 0.0f;
      }
    }
  }
}

// ---------- f16 2-split: W fp32 [N,K] -> Wc f16 [N, 2K] = [hi | lo*2^12] ---
__global__ __launch_bounds__(256) void split2_kernel(
    const float* __restrict__ W, f16* __restrict__ Wc, int total, int K) {
  const int idx = blockIdx.x * 256 + threadIdx.x;
  if (idx < total) {
    const int n = idx / K;
    const int k = idx - n * K;
    const float w64 = W[idx] * 64.0f;
    const f16 hi = (f16)w64;
    const float r = w64 - (float)hi;
    const f16 lo = (f16)(r * 4096.0f);
    const size_t base = (size_t)n * 2 * K + k;
    Wc[base] = hi;
    Wc[base + K] = lo;
  }
}

// ---------- lif1: full 25-step recurrence, cur1 is step-invariant ----------
__global__ __launch_bounds__(256) void lif1_kernel(
    const float* __restrict__ cur1, f16* __restrict__ s1_all) {
  const int i0 = (blockIdx.x * 256 + (int)threadIdx.x) * 4;
  const float4 c = *(const float4*)(cur1 + i0);
  const float ca[4] = {c.x, c.y, c.z, c.w};
  float m[4] = {0.0f, 0.0f, 0.0f, 0.0f};
  for (int st = 0; st < 25; ++st) {
    half4 sv;
#pragma unroll
    for (int j = 0; j < 4; ++j) {
      const float mo = m[j];
      const float reset = (mo - 1.0f > 0.0f) ? 1.0f : 0.0f;
      float mn = __fmul_rn(0.95f, mo);
      mn = __fadd_rn(mn, ca[j]);
      mn = __fsub_rn(mn, reset);
      m[j] = mn;
      sv[j] = (f16)((mn - 1.0f > 0.0f) ? 1.0f : 0.0f);
    }
    *(half4*)(s1_all + (size_t)st * (B_TOTAL * 128) + i0) = sv;
  }
}

// ---------- per-layer GEMM + LIF, 25 steps, fully-resident B panel ---------
// Block tile (64*MF) x (16*NF); 4 waves = 4 m-strips of 16*MF rows; wave
// tile (16*MF) x (16*NF) via 16x16x32 MFMA (MF m-frags x NF n-frags, hi+lo).
// LDS: NK swizzled K-64 tiles, staged once, single barrier; 25-step loop is
// barrier-free. Flat space it = st*NK + kt walked with an ASM-PINNED
// depth-4 register pipeline (see header). mem state in registers.
// XCD mapping: NMT = 2048/(64*MF) m-tiles: m-tile = lb%NMT -> XCD = m%8.
template <int NK, int NF, int MF>
__global__ __launch_bounds__(256) void layer_kernel(
    const f16* __restrict__ A_all,   // [25][2048][K] input spikes
    const f16* __restrict__ Wc,      // [N][2K] = [hi | lo]
    const float* __restrict__ bias,
    f16* __restrict__ spk_out,       // [25][2048][N]   (mode 0)
    float* __restrict__ sr, float* __restrict__ mr,  // [25][2048][N] (mode 1)
    int N, int K, int mode) {
  extern __shared__ f16 Bsm[];
  constexpr int TROWS = 32 * NF;    // rows per K-tile (hi block + lo block)
  constexpr int TILE = TROWS * 64;  // f16 per K-tile
  constexpr int MB = 64 * MF;       // block rows
  constexpr int NMT = 2048 / MB;    // m-tiles (16 for MF=2, 8 for MF=4)
  constexpr int LOG_NK = (NK == 2) ? 1 : (NK == 4) ? 2 : (NK == 8) ? 3 : 4;
  constexpr int TOT = 25 * NK;      // flat iteration count
  constexpr int L = MF * 2;         // global loads per tile

  const int t = threadIdx.x;
  const int lane = t & 63;
  const int wm = t >> 6;            // m-strip 0..3
  const int lb = blockIdx.x;
  const int m0 = (lb & (NMT - 1)) * MB;  // XCD = lb%8 = m-tile%8
  const int n0 = (lb / NMT) * (16 * NF);
  const int lrow = t >> 3;          // 0..31 staging row
  const int lk = (t & 7) * 8;       // staging f16 col chunk
  const int K2 = 2 * K;

  // bias per owned column (N is an exact multiple of the n-tile)
  float bias_r[NF];
#pragma unroll
  for (int j = 0; j < NF; ++j) bias_r[j] = bias[n0 + j * 16 + (lane & 15)];

  // accumulators + membrane state (registers, persistent across 25 steps)
  f32x4 acch[MF][NF], accl[MF][NF], memr[MF][NF];
#pragma unroll
  for (int i = 0; i < MF; ++i)
#pragma unroll
    for (int j = 0; j < NF; ++j) memr[i][j] = 0.0f;

  // ---- stage the ENTIRE panel once (global -> reg -> swizzled ds_write) ----
#pragma unroll
  for (int kt = 0; kt < NK; ++kt) {
    f16* T = Bsm + kt * TILE;
    if constexpr (NF == 2) {
      const int r = lrow;
      const f16* src = Wc + (size_t)(n0 + r) * K2 + kt * 64 + lk;
      const short8 vh = *(const short8*)(src);
      const short8 vl = *(const short8*)(src + K);
      const int sw = lk ^ ((r & 7) << 3);
      *(short8*)(T + r * 64 + sw) = vh;
      *(short8*)(T + (32 + r) * 64 + sw) = vl;  // (32+r)&7 == r&7
    } else {
      const int r = lrow;
      const int c = r & 15;
      const f16* src =
          Wc + (size_t)(n0 + c) * K2 + ((r < 16) ? 0 : K) + kt * 64 + lk;
      const short8 v = *(const short8*)(src);
      const int sw = lk ^ ((r & 7) << 3);
      *(short8*)(T + r * 64 + sw) = v;
    }
  }
  __syncthreads();  // the ONLY barrier

  const f16* Abase = A_all + (size_t)(m0 + wm * (16 * MF) + (lane & 15)) * K +
                     ((lane >> 4) * 8);
  const size_t Astep = (size_t)B_TOTAL * K;

  const int col = lane & 15;
  const int rbase = (lane >> 4) * 4;

  // issue all L A-fragment loads of flat tile j into buf (asm, order-pinned)
  auto load_tile = [&](int j, half8 (&buf)[MF][2]) {
    const f16* At =
        Abase + (size_t)(j >> LOG_NK) * Astep + (j & (NK - 1)) * 64;
#pragma unroll
    for (int i = 0; i < MF; ++i)
#pragma unroll
      for (int s = 0; s < 2; ++s)
        buf[i][s] = gld16(At + (size_t)i * 16 * K + s * 32);
  };

  // plain (compiler-managed) load, used only on the NK==2 path
  auto load_tile_plain = [&](int j, half8 (&buf)[MF][2]) {
    const f16* At =
        Abase + (size_t)(j >> LOG_NK) * Astep + (j & (NK - 1)) * 64;
#pragma unroll
    for (int i = 0; i < MF; ++i)
#pragma unroll
      for (int s = 0; s < 2; ++s)
        buf[i][s] = *(const half8*)(At + (size_t)i * 16 * K + s * 32);
  };

  // consume flat tile j's A fragments against the LDS-resident B tile
  auto compute_tile = [&](int j, const half8 (&buf)[MF][2]) {
    const f16* T = Bsm + (j & (NK - 1)) * TILE;
#pragma unroll
    for (int s = 0; s < 2; ++s) {
      const int kb = s * 32 + (lane >> 4) * 8;
      half8 bh[NF], bl[NF];
#pragma unroll
      for (int jj = 0; jj < NF; ++jj) {
        const int rh = jj * 16 + col;
        const int rl = 16 * NF + rh;
        bh[jj] = *(const half8*)(T + rh * 64 + (kb ^ ((rh & 7) << 3)));
        bl[jj] = *(const half8*)(T + rl * 64 + (kb ^ ((rl & 7) << 3)));
      }
#pragma unroll
      for (int i = 0; i < MF; ++i)
#pragma unroll
        for (int jj = 0; jj < NF; ++jj) {
          acch[i][jj] = __builtin_amdgcn_mfma_f32_16x16x32_f16(
              buf[i][s], bh[jj], acch[i][jj], 0, 0, 0);
          accl[i][jj] = __builtin_amdgcn_mfma_f32_16x16x32_f16(
              buf[i][s], bl[jj], accl[i][jj], 0, 0, 0);
        }
    }
  };

  // epilogue: combine hi/lo, bias+relu, LIF update, store, zero accs
  auto epilogue = [&](int st) {
#pragma unroll
    for (int i = 0; i < MF; ++i) {
#pragma unroll
      for (int r = 0; r < 4; ++r) {
        const int m = m0 + wm * (16 * MF) + i * 16 + rbase + r;
#pragma unroll
        for (int j = 0; j < NF; ++j) {
          const int n = n0 + j * 16 + col;
          const float v =
              __fadd_rn(acch[i][j][r], __fmul_rn(accl[i][j][r], LO_SCALE));
          float cur = __fadd_rn(__fmul_rn(v, ACC_SCALE), bias_r[j]);
          cur = cur > 0.0f ? cur : 0.0f;
          const float mo = memr[i][j][r];
          const float reset = (mo - 1.0f > 0.0f) ? 1.0f : 0.0f;
          float mn = __fmul_rn(0.95f, mo);
          mn = __fadd_rn(mn, cur);
          mn = __fsub_rn(mn, reset);
          memr[i][j][r] = mn;
          const float s = (mn - 1.0f > 0.0f) ? 1.0f : 0.0f;
          const size_t idx =
              (size_t)st * (B_TOTAL * (size_t)N) + (size_t)m * N + n;
          if (mode == 1) {
            sr[idx] = s;
            mr[idx] = tanhf(mn);
          } else {
            spk_out[idx] = (f16)s;
          }
        }
      }
    }
#pragma unroll
    for (int i = 0; i < MF; ++i)
#pragma unroll
      for (int j = 0; j < NF; ++j) {
        acch[i][j] = 0.0f;
        accl[i][j] = 0.0f;
      }
  };

#pragma unroll
  for (int i = 0; i < MF; ++i)
#pragma unroll
    for (int j = 0; j < NF; ++j) {
      acch[i][j] = 0.0f;
      accl[i][j] = 0.0f;
    }

  half8 b0[MF][2], b1[MF][2], b2[MF][2], b3[MF][2];

  if constexpr (NK == 2) {
    // ---- small-layer path (TOT=50): plain loads, depth-4 rotation ----
    load_tile_plain(0, b0);
    load_tile_plain(1, b1);
    load_tile_plain(2, b2);
    load_tile_plain(3, b3);
    int st = 0;
    for (int j = 0; j < 48; j += 4) {
      compute_tile(j, b0);
      if (j + 4 < TOT) load_tile_plain(j + 4, b0);
      if (((j + 1) & (NK - 1)) == 0) { epilogue(st); ++st; }
      compute_tile(j + 1, b1);
      if (j + 5 < TOT) load_tile_plain(j + 5, b1);
      if (((j + 2) & (NK - 1)) == 0) { epilogue(st); ++st; }
      compute_tile(j + 2, b2);
      if (j + 6 < TOT) load_tile_plain(j + 6, b2);
      if (((j + 3) & (NK - 1)) == 0) { epilogue(st); ++st; }
      compute_tile(j + 3, b3);
      if (j + 7 < TOT) load_tile_plain(j + 7, b3);
      if (((j + 4) & (NK - 1)) == 0) { epilogue(st); ++st; }
    }
    compute_tile(48, b0);
    compute_tile(49, b1);
    epilogue(st);
  } else {
    // ---- ASM-PINNED depth-4 pipeline (TOT % 4 == 0) ----
    load_tile(0, b0);
    load_tile(1, b1);
    load_tile(2, b2);
    load_tile(3, b3);   // 4L loads outstanding
    int st = 0;
#pragma unroll 1
    for (int j = 0; j < TOT - 4; j += 4) {
      vmwait<3 * L>(); compute_tile(j + 0, b0); load_tile(j + 4, b0);
      if (((j + 1) & (NK - 1)) == 0) { epilogue(st); ++st; }
      vmwait<3 * L>(); compute_tile(j + 1, b1); load_tile(j + 5, b1);
      if (((j + 2) & (NK - 1)) == 0) { epilogue(st); ++st; }
      vmwait<3 * L>(); compute_tile(j + 2, b2); load_tile(j + 6, b2);
      if (((j + 3) & (NK - 1)) == 0) { epilogue(st); ++st; }
      vmwait<3 * L>(); compute_tile(j + 3, b3); load_tile(j + 7, b3);
      if (((j + 4) & (NK - 1)) == 0) { epilogue(st); ++st; }
    }
    // tail body j = TOT-4: no refills, drain 3L -> 2L -> L -> 0
    vmwait<3 * L>(); compute_tile(TOT - 4, b0);
    vmwait<2 * L>(); compute_tile(TOT - 3, b1);
    vmwait<1 * L>(); compute_tile(TOT - 2, b2);
    vmwait<0>();     compute_tile(TOT - 1, b3);
    epilogue(st);
  }
}

// ---------------------------------------------------------------------------
extern "C" void kernel_launch(void* const* d_in, const int* in_sizes, int n_in,
                              void* d_out, int out_size, void* d_ws,
                              size_t ws_size, hipStream_t stream) {
  const float* x = (const float*)d_in[0];
  const float* W[5];
  const float* bi[5];
  for (int i = 0; i < 5; ++i) {
    W[i] = (const float*)d_in[1 + 2 * i];
    bi[i] = (const float*)d_in[2 + 2 * i];
  }

  const int B = B_TOTAL;
  const int Ns[5] = {128, 256, 512, 1024, 784};
  const int Ks[5] = {100, 128, 256, 512, 1024};

  char* ws = (char*)d_ws;
  size_t off = 0;
  auto alloc = [&](size_t bytes) {
    void* p = ws + off;
    off = (off + bytes + 255) & ~(size_t)255;
    return p;
  };

  float* cur1 = (float*)alloc((size_t)B * 128 * 4);
  // all-step spike buffers: s{l}[25][B][N_l] f16
  f16* s1 = (f16*)alloc((size_t)25 * B * 128 * 2);
  f16* s2 = (f16*)alloc((size_t)25 * B * 256 * 2);
  f16* s3 = (f16*)alloc((size_t)25 * B * 512 * 2);
  f16* s4 = (f16*)alloc((size_t)25 * B * 1024 * 2);
  f16* Wc[5];
  for (int i = 1; i < 5; ++i)
    Wc[i] = (f16*)alloc((size_t)Ns[i] * Ks[i] * 2 * 2);

  float* outF = (float*)d_out;
  float* spk_rec = outF;
  float* mem_rec = outF + (size_t)25 * B * 784;

  // 2-split weights for layers 2..5
  for (int i = 1; i < 5; ++i) {
    const int total = Ns[i] * Ks[i];
    split2_kernel<<<(total + 255) / 256, 256, 0, stream>>>(W[i], Wc[i], total,
                                                           Ks[i]);
  }

  // layer-1 current: relu(x @ W1^T + b1), computed once (x is step-invariant)
  gemm_relu_f32_kernel<<<dim3(2, B / 64), 256, 0, stream>>>(x, W[0], bi[0],
                                                            cur1, 128, 100);

  // layer-1 LIF: full 25-step recurrence (cur1 fixed, mem in registers)
  lif1_kernel<<<(B * 128) / 1024, 256, 0, stream>>>(cur1, s1);

  // layers 2..5: one kernel each, 25 steps internal, mem in registers.
  // grid = NMT m-tiles x (N/(16*NF)) n-tiles; LDS = NK*NF*4096 bytes.
  layer_kernel<2, 2, 2><<<16 * 8, 256, 2 * 2 * 4096, stream>>>(
      s1, Wc[1], bi[1], s2, nullptr, nullptr, 256, 128, 0);
  layer_kernel<4, 2, 2><<<16 * 16, 256, 4 * 2 * 4096, stream>>>(
      s2, Wc[2], bi[2], s3, nullptr, nullptr, 512, 256, 0);
  layer_kernel<8, 2, 2><<<16 * 32, 256, 8 * 2 * 4096, stream>>>(
      s3, Wc[3], bi[3], s4, nullptr, nullptr, 1024, 512, 0);
  layer_kernel<16, 1, 4><<<8 * 49, 256, 16 * 1 * 4096, stream>>>(
      s4, Wc[4], bi[4], nullptr, spk_rec, mem_rec, 784, 1024, 1);
}

// Round 11
// 1273.933 us; speedup vs baseline: 1.0528x; 1.0528x over previous
//
#include <hip/hip_runtime.h>
#include <math.h>

// SNN: 5 LIF layers, B=2048, dims 100->128->256->512->1024->784, 25 steps.
// Round 18: DECOUPLE. Rounds 13-17: three pipelining mechanisms (src depth-2,
// copy-free depth-4, asm+counted-vmcnt) all null at ~753us, MfmaUtil 8.8%.
// The invariant: fused per-layer kernels run 1.5 waves/SIMD with one serial
// 400-iteration chain per block -- no TLP, and ILP can't substitute.
// Fix: s_{l-1} for ALL 25 steps exists before layer l runs, so layer l's
// GEMM is ONE [51200,K]x[K,N] GEMM (grid 3200-6400 blocks, ~3 waves/SIMD,
// standard dbuf-LDS-B + direct-A structure), writing cur=relu(v*SC+bias) in
// exact f32. A separate BW-bound rec_kernel then runs the 25-step LIF per
// (b,n) column in registers (read cur[25], write spikes / sr+mr).
// cur is chunked over N adaptively against ws_size (floor +13MB over the
// proven 214MB footprint). Numerics bit-identical: same K-order, same MFMA
// sequence, f32 cur round-trip exact, same LIF op chain.

typedef _Float16 f16;
typedef __attribute__((ext_vector_type(8))) short short8;
typedef __attribute__((ext_vector_type(8))) _Float16 half8;
typedef __attribute__((ext_vector_type(4))) _Float16 half4;
typedef __attribute__((ext_vector_type(4))) float f32x4;

#define B_TOTAL 2048
#define M_TOTAL (25 * 2048)      // 51200 flattened (step, batch) rows
#define LO_SCALE 2.44140625e-4f  // 2^-12, undoes the lo x2^12 storage scale
#define ACC_SCALE 0.015625f      // 2^-6, undoes the x64 weight pre-scale

// ---------- fp32 64x64 GEMM + relu (layer-1 current, runs once) ------------
__global__ __launch_bounds__(256) void gemm_relu_f32_kernel(
    const float* __restrict__ h, const float* __restrict__ W,
    const float* __restrict__ bias, float* __restrict__ out, int N, int K) {
  __shared__ float As[16][64];
  __shared__ float Bs[16][64];

  const int t = threadIdx.x;
  const int tx = t & 15;
  const int ty = t >> 4;
  const int m0 = blockIdx.y * 64;
  const int n0 = blockIdx.x * 64;
  const int lr = t >> 2;
  const int lc = (t & 3) * 4;

  float acc[4][4];
#pragma unroll
  for (int i = 0; i < 4; ++i)
#pragma unroll
    for (int j = 0; j < 4; ++j) acc[i][j] = 0.0f;

  const int ktiles = (K + 15) / 16;
  for (int kt = 0; kt < ktiles; ++kt) {
    const int kbase = kt * 16;
    {
      const float* src = h + (size_t)(m0 + lr) * K + kbase + lc;
#pragma unroll
      for (int j = 0; j < 4; ++j) {
        const int kg = kbase + lc + j;
        As[lc + j][lr] = (kg < K) ? src[j] : 0.0f;
      }
    }
    {
      const int nr = n0 + lr;
      const float* src = W + (size_t)nr * K + kbase + lc;
#pragma unroll
      for (int j = 0; j < 4; ++j) {
        const int kg = kbase + lc + j;
        Bs[lc + j][lr] = (nr < N && kg < K) ? src[j] : 0.0f;
      }
    }
    __syncthreads();
#pragma unroll
    for (int k = 0; k < 16; ++k) {
      float a[4], bb[4];
#pragma unroll
      for (int i = 0; i < 4; ++i) a[i] = As[k][ty * 4 + i];
#pragma unroll
      for (int j = 0; j < 4; ++j) bb[j] = Bs[k][tx * 4 + j];
#pragma unroll
      for (int i = 0; i < 4; ++i)
#pragma unroll
        for (int j = 0; j < 4; ++j) acc[i][j] = fmaf(a[i], bb[j], acc[i][j]);
    }
    __syncthreads();
  }

#pragma unroll
  for (int i = 0; i < 4; ++i) {
    const int m = m0 + ty * 4 + i;
#pragma unroll
    for (int j = 0; j < 4; ++j) {
      const int n = n0 + tx * 4 + j;
      if (n < N) {
        float cur = acc[i][j] + bias[n];
        out[(size_t)m * N + n] = cur > 0.0f ? cur : 0.0f;
      }
    }
  }
}

// ---------- f16 2-split: W fp32 [N,K] -> Wc f16 [N, 2K] = [hi | lo*2^12] ---
__global__ __launch_bounds__(256) void split2_kernel(
    const float* __restrict__ W, f16* __restrict__ Wc, int total, int K) {
  const int idx = blockIdx.x * 256 + threadIdx.x;
  if (idx < total) {
    const int n = idx / K;
    const int k = idx - n * K;
    const float w64 = W[idx] * 64.0f;
    const f16 hi = (f16)w64;
    const float r = w64 - (float)hi;
    const f16 lo = (f16)(r * 4096.0f);
    const size_t base = (size_t)n * 2 * K + k;
    Wc[base] = hi;
    Wc[base + K] = lo;
  }
}

// ---------- lif1: full 25-step recurrence, cur1 is step-invariant ----------
__global__ __launch_bounds__(256) void lif1_kernel(
    const float* __restrict__ cur1, f16* __restrict__ s1_all) {
  const int i0 = (blockIdx.x * 256 + (int)threadIdx.x) * 4;
  const float4 c = *(const float4*)(cur1 + i0);
  const float ca[4] = {c.x, c.y, c.z, c.w};
  float m[4] = {0.0f, 0.0f, 0.0f, 0.0f};
  for (int st = 0; st < 25; ++st) {
    half4 sv;
#pragma unroll
    for (int j = 0; j < 4; ++j) {
      const float mo = m[j];
      const float reset = (mo - 1.0f > 0.0f) ? 1.0f : 0.0f;
      float mn = __fmul_rn(0.95f, mo);
      mn = __fadd_rn(mn, ca[j]);
      mn = __fsub_rn(mn, reset);
      m[j] = mn;
      sv[j] = (f16)((mn - 1.0f > 0.0f) ? 1.0f : 0.0f);
    }
    *(half4*)(s1_all + (size_t)st * (B_TOTAL * 128) + i0) = sv;
  }
}

// ---------- big hi/lo GEMM: cur[m, n-n_off] = relu(A·Wc^T * SC + bias) -----
// Tiles 128m x 64n, 4 waves (2m x 2n), wave tile 64x32 (4 m-frags x 2
// n-frags, hi+lo accumulators). A fragments direct from global (L1/L2-hot:
// each m-slice shared by all n-tiles on one XCD since nbm=400 %8==0).
// B (hi+lo) double-buffered in LDS, swizzled, 1 barrier per K-64 tile.
// High occupancy does the latency hiding (grid 1600-6400 blocks).
__global__ __launch_bounds__(256) void gemm_hl_kernel(
    const f16* __restrict__ A,    // [51200][K]
    const f16* __restrict__ Wc,   // [Npad][2K] = [hi | lo], pad rows zero
    const float* __restrict__ bias,
    float* __restrict__ cur,      // [51200][CW] chunk
    int N, int K, int n_off, int CW, int nbm) {
  __shared__ f16 Bs[2][2][64][64];  // [buf][hi/lo][n-row][k]

  const int t = threadIdx.x;
  const int lane = t & 63;
  const int w = t >> 6;
  const int wm = w >> 1;
  const int wn = w & 1;
  const int lb = blockIdx.x;
  const int mt = lb % nbm;          // nbm=400 %8==0 -> XCD = mt%8
  const int nt = lb / nbm;
  const int m0 = mt * 128;
  const int ng0 = n_off + nt * 64;
  const int NKT = K >> 6;
  const int q = lane >> 4;
  const int c = lane & 15;
  const int lrow = t >> 3;          // 0..31 staging row
  const int lk = (t & 7) * 8;       // staging f16 col chunk
  const int K2 = 2 * K;

  float bias_r[2];
#pragma unroll
  for (int j = 0; j < 2; ++j) {
    const int n = ng0 + wn * 32 + j * 16 + c;
    bias_r[j] = (n < N) ? bias[n] : 0.0f;
  }

  f32x4 acch[4][2], accl[4][2];
#pragma unroll
  for (int i = 0; i < 4; ++i)
#pragma unroll
    for (int j = 0; j < 2; ++j) {
      acch[i][j] = 0.0f;
      accl[i][j] = 0.0f;
    }

  const f16* Aln = A + (size_t)(m0 + wm * 64 + c) * K + q * 8;

  short8 vh[2], vl[2];
  auto ldB = [&](int kt) {
#pragma unroll
    for (int i2 = 0; i2 < 2; ++i2) {
      const int r = lrow + 32 * i2;
      const f16* src = Wc + (size_t)(ng0 + r) * K2 + kt * 64 + lk;
      vh[i2] = *(const short8*)(src);
      vl[i2] = *(const short8*)(src + K);
    }
  };
  auto wrB = [&](int buf) {
#pragma unroll
    for (int i2 = 0; i2 < 2; ++i2) {
      const int r = lrow + 32 * i2;
      const int sw = lk ^ ((r & 7) << 3);
      *(short8*)(&Bs[buf][0][r][sw]) = vh[i2];
      *(short8*)(&Bs[buf][1][r][sw]) = vl[i2];
    }
  };
  auto compute = [&](int buf, int kt) {
    const f16* At = Aln + kt * 64;
    half8 af[4][2];
#pragma unroll
    for (int i = 0; i < 4; ++i)
#pragma unroll
      for (int s = 0; s < 2; ++s)
        af[i][s] = *(const half8*)(At + (size_t)i * 16 * K + s * 32);
#pragma unroll
    for (int s = 0; s < 2; ++s) {
      const int kb = s * 32 + q * 8;
      half8 bh[2], bl[2];
#pragma unroll
      for (int j = 0; j < 2; ++j) {
        const int rr = wn * 32 + j * 16 + c;
        const int sw = kb ^ ((rr & 7) << 3);
        bh[j] = *(const half8*)(&Bs[buf][0][rr][sw]);
        bl[j] = *(const half8*)(&Bs[buf][1][rr][sw]);
      }
#pragma unroll
      for (int i = 0; i < 4; ++i)
#pragma unroll
        for (int j = 0; j < 2; ++j) {
          acch[i][j] = __builtin_amdgcn_mfma_f32_16x16x32_f16(
              af[i][s], bh[j], acch[i][j], 0, 0, 0);
          accl[i][j] = __builtin_amdgcn_mfma_f32_16x16x32_f16(
              af[i][s], bl[j], accl[i][j], 0, 0, 0);
        }
    }
  };

  ldB(0);
  wrB(0);
  __syncthreads();
  for (int kt = 0; kt < NKT; ++kt) {
    const bool more = (kt + 1 < NKT);
    if (more) ldB(kt + 1);           // issue next tile's loads early
    compute(kt & 1, kt);
    if (more) wrB((kt + 1) & 1);
    __syncthreads();
  }

  // epilogue: combine hi/lo, bias+relu, store exact f32 cur
#pragma unroll
  for (int i = 0; i < 4; ++i) {
#pragma unroll
    for (int r = 0; r < 4; ++r) {
      const int m = m0 + wm * 64 + i * 16 + q * 4 + r;
#pragma unroll
      for (int j = 0; j < 2; ++j) {
        const int n = ng0 + wn * 32 + j * 16 + c;
        if (n < N) {
          const float v =
              __fadd_rn(acch[i][j][r], __fmul_rn(accl[i][j][r], LO_SCALE));
          float cv = __fadd_rn(__fmul_rn(v, ACC_SCALE), bias_r[j]);
          cv = cv > 0.0f ? cv : 0.0f;
          cur[(size_t)m * CW + (n - n_off)] = cv;
        }
      }
    }
  }
}

// ---------- 25-step LIF recurrence over a cur chunk ------------------------
// One thread per (b, 4 consecutive n): mem in registers, 25 strided float4
// reads of cur, spike/sr/mr writes. BW-bound streaming kernel.
__global__ __launch_bounds__(256) void rec_kernel(
    const float* __restrict__ cur,   // [25*2048][CW]
    f16* __restrict__ spk,           // [25][2048][N]          (mode 0)
    float* __restrict__ sr, float* __restrict__ mr,  // [25][2048][N] (mode 1)
    int N, int n_off, int CWc, int CW, int mode) {
  const int gp = CWc >> 2;
  const int tid = blockIdx.x * 256 + (int)threadIdx.x;
  if (tid >= B_TOTAL * gp) return;
  const int b = tid / gp;
  const int g = tid - b * gp;
  const float* src = cur + (size_t)b * CW + g * 4;
  const int n = n_off + g * 4;
  float m4[4] = {0.0f, 0.0f, 0.0f, 0.0f};
  for (int st = 0; st < 25; ++st) {
    const float4 c4 = *(const float4*)(src + (size_t)st * B_TOTAL * CW);
    const float ca[4] = {c4.x, c4.y, c4.z, c4.w};
    float sp[4];
#pragma unroll
    for (int j = 0; j < 4; ++j) {
      const float mo = m4[j];
      const float reset = (mo - 1.0f > 0.0f) ? 1.0f : 0.0f;
      float mn = __fmul_rn(0.95f, mo);
      mn = __fadd_rn(mn, ca[j]);
      mn = __fsub_rn(mn, reset);
      m4[j] = mn;
      sp[j] = (mn - 1.0f > 0.0f) ? 1.0f : 0.0f;
    }
    const size_t ob = (size_t)(st * B_TOTAL + b) * N + n;
    if (mode == 1) {
      float4 s4v;
      s4v.x = sp[0]; s4v.y = sp[1]; s4v.z = sp[2]; s4v.w = sp[3];
      float4 t4;
      t4.x = tanhf(m4[0]); t4.y = tanhf(m4[1]);
      t4.z = tanhf(m4[2]); t4.w = tanhf(m4[3]);
      *(float4*)(sr + ob) = s4v;
      *(float4*)(mr + ob) = t4;
    } else {
      half4 h4;
#pragma unroll
      for (int j = 0; j < 4; ++j) h4[j] = (f16)sp[j];
      *(half4*)(spk + ob) = h4;
    }
  }
}

// ---------------------------------------------------------------------------
extern "C" void kernel_launch(void* const* d_in, const int* in_sizes, int n_in,
                              void* d_out, int out_size, void* d_ws,
                              size_t ws_size, hipStream_t stream) {
  const float* x = (const float*)d_in[0];
  const float* W[5];
  const float* bi[5];
  for (int i = 0; i < 5; ++i) {
    W[i] = (const float*)d_in[1 + 2 * i];
    bi[i] = (const float*)d_in[2 + 2 * i];
  }

  const int B = B_TOTAL;
  const int Ns[5] = {128, 256, 512, 1024, 784};
  const int Ks[5] = {100, 128, 256, 512, 1024};

  char* ws = (char*)d_ws;
  size_t off = 0;
  auto alloc = [&](size_t bytes) {
    void* p = ws + off;
    off = (off + bytes + 255) & ~(size_t)255;
    return p;
  };

  float* cur1 = (float*)alloc((size_t)B * 128 * 4);
  // all-step spike buffers: s{l}[25][B][N_l] f16
  f16* s[4];
  for (int i = 0; i < 4; ++i) s[i] = (f16*)alloc((size_t)25 * B * Ns[i] * 2);
  // padded hi/lo weights (pad rows to x64, zero-filled)
  f16* Wc[5];
  const size_t wcStart = off;
  int Npad[5];
  for (int i = 1; i < 5; ++i) {
    Npad[i] = (Ns[i] + 63) & ~63;
    Wc[i] = (f16*)alloc((size_t)Npad[i] * 2 * Ks[i] * 2);
  }
  const size_t wcBytes = off - wcStart;

  // adaptive cur chunk width (f32 [51200][CW]); floor CW=64 -> +13MB only
  const size_t avail = (ws_size > off) ? (ws_size - off) : 0;
  int CW = 512;
  while (CW > 64 && (size_t)M_TOTAL * CW * 4 > avail) CW >>= 1;
  float* cur = (float*)alloc((size_t)M_TOTAL * CW * 4);

  float* outF = (float*)d_out;
  float* spk_rec = outF;
  float* mem_rec = outF + (size_t)25 * B * 784;

  // zero Wc pad rows, then 2-split weights for layers 2..5
  hipMemsetAsync(ws + wcStart, 0, wcBytes, stream);
  for (int i = 1; i < 5; ++i) {
    const int total = Ns[i] * Ks[i];
    split2_kernel<<<(total + 255) / 256, 256, 0, stream>>>(W[i], Wc[i], total,
                                                           Ks[i]);
  }

  // layer-1 current: relu(x @ W1^T + b1), computed once (x is step-invariant)
  gemm_relu_f32_kernel<<<dim3(2, B / 64), 256, 0, stream>>>(x, W[0], bi[0],
                                                            cur1, 128, 100);

  // layer-1 LIF: full 25-step recurrence (cur1 fixed, mem in registers)
  lif1_kernel<<<(B * 128) / 1024, 256, 0, stream>>>(cur1, s[0]);

  // layers 2..5: big GEMM over all steps (M=51200) + streaming recurrence,
  // chunked over N to bound the cur workspace.
  const int nbm = M_TOTAL / 128;  // 400
  for (int i = 1; i < 5; ++i) {
    const int N = Ns[i], K = Ks[i];
    const f16* Ain = s[i - 1];
    for (int n_off = 0; n_off < N; n_off += CW) {
      const int CWc = (N - n_off < CW) ? (N - n_off) : CW;
      const int nbn = (CWc + 63) / 64;
      gemm_hl_kernel<<<nbm * nbn, 256, 0, stream>>>(Ain, Wc[i], bi[i], cur, N,
                                                    K, n_off, CW, nbm);
      const int nth = B * (CWc / 4);
      if (i < 4) {
        rec_kernel<<<(nth + 255) / 256, 256, 0, stream>>>(
            cur, s[i], nullptr, nullptr, N, n_off, CWc, CW, 0);
      } else {
        rec_kernel<<<(nth + 255) / 256, 256, 0, stream>>>(
            cur, nullptr, spk_rec, mem_rec, N, n_off, CWc, CW, 1);
      }
    }
  }
}